// Round 24
// baseline (82.356 us; speedup 1.0000x reference)
//
#include <hip/hip_runtime.h>
#include <float.h>

#define NSEG 8
#define SEGLEN 1024   // B*Ls*H*D = 1*4*8*32
#define BIGV 1e30f    // "infinity" for invalid DP cells
#define PADV 1e18f    // x-pad sentinel: huge cost, no overflow over a chunk

#define NW 4          // strips per pair; wave owns 256 cols
#define CH 64         // steps per chunk (one flag handshake per chunk)
#define NCH 17        // local steps 0..1087 (lane 63 hits row 1023 at t=1086)
#define XLEN 1152     // xl[t] = x[t] for t<1024, else PADV
#define BOFF 67       // bnd[..][row + 67]; preload base 64tc+68 16B-aligned
#define BSTRIDE 1160  // max read index 64*16+68+63 = 1155

#define DPPF(OLD, SRC, CTRL, RM, BM, BC)                                      \
    __int_as_float(__builtin_amdgcn_update_dpp(                               \
        __float_as_int(OLD), __float_as_int(SRC), CTRL, RM, BM, BC))
// lane i <- lane i-1; lane 0 <- OLD[lane 0]   (validated R2-R23)
#define WSHIFT1(OLD, SRC) DPPF(OLD, SRC, 0x138, 0xF, 0xF, false)

// Lane-skewed systolic DTW, TWO pairs per 512-thread block (R24).
// Waves 0-3 run pair 2b, waves 4-7 run pair 2b+1 -- each SIMD hosts two
// waves from INDEPENDENT pipelines, so the 4-cyc VALU dependent latency of
// one wave is filled by the other (R9/R10 measured combined SIMD throughput
// ~2.65 cyc/inst vs ~4.4 single-wave; R23's bout[] register buffering
// spilled to scratch -- reverted to R22's per-step ds_write + dump sink).
// Per pair: wave ws owns cols [256ws,256ws+256); lane L owns c_e=256ws+4L+e.
// At local step t, lane L computes ROW r = t - L of its four columns:
//   c0 = |x[r]-y0| + min3(P0(up), lf(left), dgl(diag))
//   c_e = |x[r]-y_e| + min3(P_e, c_{e-1}, P_{e-1})
// lf/dgl arrive via one end-of-step wf_sr1 of c3; x travels the same way.
// Injects are wave-uniform -> per-chunk register preloads via uniform
// ds_read_b128 (R22 win). Garbage rows (r<0,r>1023) carry PADV-scale costs.
// Lane 63 writes c3 (row r=t-63) to bnd[pr][ws+1][64tc+4+s] per step
// (others hit the shared dump sink); monotone chunk-counter handshake with
// lag 2 per pair (consumer chunk tc reads bnd rows <= 64tc+64).
__global__ __launch_bounds__(512) void dtw_2p_kernel(const float* __restrict__ q,
                                                     const float* __restrict__ kk,
                                                     float* __restrict__ dists) {
    __shared__ float xl[2][XLEN];
    __shared__ float bnd[2][NW + 1][BSTRIDE];  // [pr][0] = BIGV region
    __shared__ float dump[128];                // shared sink (racy writes OK)
    __shared__ int flagsA[2][NW + 1];          // [pr][0]=sentinel
    const int tid = threadIdx.x;
    const int lane = tid & 63;
    const int wva = tid >> 6;        // 0..7
    const int pr = wva >> 2;         // pair half: 0 or 1
    const int ws = wva & 3;          // strip within pair
    const int htid = tid & 255;      // tid within the half
    const int pair = blockIdx.x * 2 + pr;       // 0..63
    const float* __restrict__ x = q + (pair >> 3) * SEGLEN;
    const float* __restrict__ y = kk + (pair & 7) * SEGLEN;

    // each 256-thread half stages its own pair's arrays
    for (int t = htid; t < XLEN; t += 256) xl[pr][t] = (t < SEGLEN) ? x[t] : PADV;
    // flat index 66 = bnd[pr][0][BOFF-1] = virtual corner D[-1,-1]=0; rest BIGV.
    for (int t = htid; t < (NW + 1) * BSTRIDE; t += 256)
        (&bnd[pr][0][0])[t] = (t == BOFF - 1) ? 0.f : BIGV;
    if (htid < NW + 1) flagsA[pr][htid] = (htid == 0) ? 0x7FFFFFFF : 0;

    const float4 y4 = *(const float4*)(y + ws * 256 + lane * 4);
    const float yv0 = y4.x, yv1 = y4.y, yv2 = y4.z, yv3 = y4.w;

    __syncthreads();   // the only block-wide barrier

    const float* __restrict__ br = &bnd[pr][ws][0];  // left neighbor boundary

    // wait for the first 2 producer chunks before reading init boundary
    {
        const int need0 = (NCH < 2) ? NCH : 2;
        while (__hip_atomic_load(&flagsA[pr][ws], __ATOMIC_ACQUIRE,
                                 __HIP_MEMORY_SCOPE_WORKGROUP) < need0)
            __builtin_amdgcn_s_sleep(1);
    }
    float P0 = BIGV, P1 = BIGV, P2 = BIGV, P3 = BIGV, xreg = PADV;
    float lf = br[BOFF];       // D[0, 256ws-1] (strip 0: BIGV); real only lane 0
    float dgl = br[BOFF - 1];  // D[-1,256ws-1] (strip 0: corner 0)

// One systolic step; injects come straight from the preloaded register
// arrays (static index s) as DPP old-operands.
#define STEP(s) {                                                             \
    xreg = WSHIFT1(x64u[(s)], xreg);                                          \
    const float c0n = fabsf(xreg - yv0) + fminf(fminf(P0, lf), dgl);          \
    const float c1n = fabsf(xreg - yv1) + fminf(fminf(P1, c0n), P0);          \
    const float c2n = fabsf(xreg - yv2) + fminf(fminf(P2, c1n), P1);          \
    const float c3n = fabsf(xreg - yv3) + fminf(fminf(P3, c2n), P2);          \
    const float n1 = WSHIFT1(b64[(s)], c3n);                                  \
    dgl = lf; lf = n1; P0 = c0n; P1 = c1n; P2 = c2n; P3 = c3n;                \
    va[(s)] = c3n;                                                            \
}
#define STEP8(s) STEP(s) STEP((s)+1) STEP((s)+2) STEP((s)+3)                  \
                 STEP((s)+4) STEP((s)+5) STEP((s)+6) STEP((s)+7)

#pragma unroll 1
    for (int tc = 0; tc < NCH; ++tc) {
        // consumer chunk tc reads bnd rows <= 64tc+64; producer writes row r
        // at its step r+63 -> needs chunk tc+1 done (flag >= tc+2), capped
        // at NCH (later indices are BIGV pad).
        const int need = (tc + 2 < NCH) ? (tc + 2) : NCH;
        while (__hip_atomic_load(&flagsA[pr][ws], __ATOMIC_ACQUIRE,
                                 __HIP_MEMORY_SCOPE_WORKGROUP) < need)
            __builtin_amdgcn_s_sleep(1);

        // uniform preloads (16B-aligned, broadcast reads):
        // x64u[s] = x[64tc+s]; b64[s] = bnd row 64tc+s+1 (index 64tc+68+s).
        float x64u[64], b64[64];
#pragma unroll
        for (int j = 0; j < 16; ++j)
            *(float4*)&x64u[4 * j] = *(const float4*)&xl[pr][64 * tc + 4 * j];
#pragma unroll
        for (int j = 0; j < 16; ++j)
            *(float4*)&b64[4 * j] = *(const float4*)&br[64 * tc + 68 + 4 * j];

        // boundary write: lane 63 (row r = 64tc+s-63) -> bnd[pr][ws+1][64tc+4+s];
        // others -> dump.
        float* va = (lane == 63) ? &bnd[pr][ws + 1][64 * tc + 4] : &dump[lane];

        STEP8(0) STEP8(8) STEP8(16) STEP8(24) STEP8(32) STEP8(40) STEP8(48) STEP8(56)

        // publish chunk tc (release orders the ds_writes above before the flag)
        __hip_atomic_store(&flagsA[pr][ws + 1], tc + 1, __ATOMIC_RELEASE,
                           __HIP_MEMORY_SCOPE_WORKGROUP);
    }
#undef STEP
#undef STEP8

    // D[1023,1023]: strip 3 lane 63 col e=3 at t=1086 (chunk 16, s=62) -> c3
    // -> bnd[pr][NW][1023+BOFF] = [1090]; read back from LDS.
    if (ws == NW - 1 && lane == 0) dists[pair] = bnd[pr][NW][1090];
}

// out[i*1024+p] = sum_j softmax_j(0.5*dists[i,:])[j] * values[j*1024+p]
__global__ __launch_bounds__(256) void softmax_out_kernel(const float* __restrict__ v,
                                                          const float* __restrict__ dists,
                                                          float* __restrict__ out) {
    const int o = blockIdx.x * blockDim.x + threadIdx.x;
    if (o >= NSEG * SEGLEN) return;
    const int i = o >> 10;
    const int p = o & 1023;

    float l[NSEG];
    float mx = -FLT_MAX;
#pragma unroll
    for (int j = 0; j < NSEG; ++j) {
        l[j] = 0.5f * dists[i * NSEG + j];
        mx = fmaxf(mx, l[j]);
    }
    float s = 0.f;
#pragma unroll
    for (int j = 0; j < NSEG; ++j) {
        l[j] = expf(l[j] - mx);
        s += l[j];
    }
    const float inv = 1.f / s;
    float acc = 0.f;
#pragma unroll
    for (int j = 0; j < NSEG; ++j) acc += (l[j] * inv) * v[j * SEGLEN + p];
    out[o] = acc;
}

extern "C" void kernel_launch(void* const* d_in, const int* in_sizes, int n_in,
                              void* d_out, int out_size, void* d_ws, size_t ws_size,
                              hipStream_t stream) {
    const float* q = (const float*)d_in[0];   // queries [1,32,8,32] f32
    const float* k = (const float*)d_in[1];   // keys
    const float* v = (const float*)d_in[2];   // values
    float* out = (float*)d_out;               // [8192] f32
    float* dists = (float*)d_ws;              // 64 floats scratch

    dtw_2p_kernel<<<dim3(NSEG * NSEG / 2), dim3(512), 0, stream>>>(q, k, dists);
    softmax_out_kernel<<<dim3((NSEG * SEGLEN + 255) / 256), dim3(256), 0, stream>>>(v, dists, out);
}

// Round 25
// 67.334 us; speedup vs baseline: 1.2231x; 1.2231x over previous
//
#include <hip/hip_runtime.h>
#include <float.h>

#define NSEG 8
#define SEGLEN 1024   // B*Ls*H*D = 1*4*8*32
#define BIGV 1e30f    // "infinity" for invalid DP cells
#define PADV 1e18f    // x-pad sentinel: huge cost, no overflow over a chunk

#define NW 4          // waves per block (256 threads); wave owns 256 cols
#define CH 64         // steps per chunk (one flag handshake per chunk)
#define NCH 17        // local steps 0..1087 (lane 63 hits row 1023 at t=1086)
#define XLEN 1152     // xl[t] = x[t] for t<1024, else PADV
#define BOFF 67       // bnd[w][row + 67]; preload base 64tc+68 is 16B-aligned
#define BSTRIDE 1160  // max read index 64*16+68+63 = 1155

#define DPPF(OLD, SRC, CTRL, RM, BM, BC)                                      \
    __int_as_float(__builtin_amdgcn_update_dpp(                               \
        __float_as_int(OLD), __float_as_int(SRC), CTRL, RM, BM, BC))
// lane i <- lane i-1; lane 0 <- OLD[lane 0]   (validated R2-R24)
#define WSHIFT1(OLD, SRC) DPPF(OLD, SRC, 0x138, 0xF, 0xF, false)

// Lane-skewed systolic DTW, 4 waves (1 per SIMD) -- R22's measured-best
// structure, hot loop byte-identical. Wave w owns cols [256w,256w+256);
// lane L owns c_e = 256w+4L+e, e in 0..3.
// At local step t, lane L computes ROW r = t - L of its four columns:
//   c0 = |x[r]-y0| + min3(P0(up), lf(left), dgl(diag))
//   c_e = |x[r]-y_e| + min3(P_e, c_{e-1}, P_{e-1})
// lf/dgl arrive via one end-of-step wf_sr1 of c3; x travels the same way.
// Measured law (R9-R24): cyc/step ~ 4.4 x inst/step at 1 wave/SIMD (latency
// cadence; chain/SGPR/DPP/packing theories all A/B-nulled; R24 showed
// 2-wave packing improves throughput but lengthens the latency-bound
// makespan). Injects are wave-uniform -> per-chunk register preloads via
// uniform ds_read_b128 (R22 win, -8.6us). R23's bout[] write buffering
// spilled to scratch (VGPR) -- per-step ds_write + dump sink retained.
// R25 (isolated A/B vs R22): softmax+output epilogue fused via last-block
// ticket (R16b-validated machinery: dists store -> threadfence -> device
// atomicAdd; the block drawing ticket 63 computes d_out) -- deletes the
// second kernel launch. Garbage rows (r<0, r>1023) carry PADV-scale costs
// acting as +inf. Monotone chunk-counter handshake with lag 2.
__global__ __launch_bounds__(256) void dtw_pl_kernel(const float* __restrict__ q,
                                                     const float* __restrict__ kk,
                                                     const float* __restrict__ vv,
                                                     float* __restrict__ out,
                                                     float* __restrict__ dists,
                                                     int* __restrict__ cnt) {
    __shared__ float xl[XLEN];
    __shared__ float bnd[NW + 1][BSTRIDE];  // bnd[0] = BIGV region for wave 0
    __shared__ float dump[128];             // sink, indices up to 125 (R8 lesson)
    __shared__ int flagsA[NW + 1];          // [0]=sentinel; [w+1]=wave w chunks done
    __shared__ int lastFlag;
    __shared__ float wgt[NSEG][NSEG];       // epilogue softmax weights
    const int tid = threadIdx.x;
    const int lane = tid & 63;
    const int wv = tid >> 6;
    const int pair = blockIdx.x;            // 0..63
    const float* __restrict__ x = q + (pair >> 3) * SEGLEN;
    const float* __restrict__ y = kk + (pair & 7) * SEGLEN;

    for (int t = tid; t < XLEN; t += 256) xl[t] = (t < SEGLEN) ? x[t] : PADV;
    // flat index 66 = bnd[0][BOFF-1] = virtual corner D[-1,-1] = 0; rest BIGV.
    for (int t = tid; t < (NW + 1) * BSTRIDE; t += 256)
        (&bnd[0][0])[t] = (t == BOFF - 1) ? 0.f : BIGV;
    if (tid < NW + 1) flagsA[tid] = (tid == 0) ? 0x7FFFFFFF : 0;
    if (tid == 0) lastFlag = 0;

    const float4 y4 = *(const float4*)(y + wv * 256 + lane * 4);
    const float yv0 = y4.x, yv1 = y4.y, yv2 = y4.z, yv3 = y4.w;

    __syncthreads();   // the only barrier before the main loop

    const float* __restrict__ br = &bnd[wv][0];   // left neighbor's boundary

    // wait for the first 2 producer chunks before reading init boundary
    {
        const int need0 = (NCH < 2) ? NCH : 2;
        while (__hip_atomic_load(&flagsA[wv], __ATOMIC_ACQUIRE,
                                 __HIP_MEMORY_SCOPE_WORKGROUP) < need0)
            __builtin_amdgcn_s_sleep(1);
    }
    float P0 = BIGV, P1 = BIGV, P2 = BIGV, P3 = BIGV, xreg = PADV;
    float lf = br[BOFF];       // D[0, 256w-1] (wave 0: BIGV); real only lane 0
    float dgl = br[BOFF - 1];  // D[-1,256w-1] (wave 0: corner 0)

// One systolic step; inject values come straight from the preloaded
// register arrays (static index s) as DPP old-operands.
#define STEP(s) {                                                             \
    xreg = WSHIFT1(x64u[(s)], xreg);                                          \
    const float c0n = fabsf(xreg - yv0) + fminf(fminf(P0, lf), dgl);          \
    const float c1n = fabsf(xreg - yv1) + fminf(fminf(P1, c0n), P0);          \
    const float c2n = fabsf(xreg - yv2) + fminf(fminf(P2, c1n), P1);          \
    const float c3n = fabsf(xreg - yv3) + fminf(fminf(P3, c2n), P2);          \
    const float n1 = WSHIFT1(b64[(s)], c3n);                                  \
    dgl = lf; lf = n1; P0 = c0n; P1 = c1n; P2 = c2n; P3 = c3n;                \
    va[(s)] = c3n;                                                            \
}
#define STEP8(s) STEP(s) STEP((s)+1) STEP((s)+2) STEP((s)+3)                  \
                 STEP((s)+4) STEP((s)+5) STEP((s)+6) STEP((s)+7)

#pragma unroll 1
    for (int tc = 0; tc < NCH; ++tc) {
        // consumer chunk tc reads bnd rows <= 64tc+64; producer writes row r
        // at its step r+63 -> needs chunk tc+1 done (flag >= tc+2), capped
        // at NCH (later indices are BIGV pad).
        const int need = (tc + 2 < NCH) ? (tc + 2) : NCH;
        while (__hip_atomic_load(&flagsA[wv], __ATOMIC_ACQUIRE,
                                 __HIP_MEMORY_SCOPE_WORKGROUP) < need)
            __builtin_amdgcn_s_sleep(1);

        // uniform preloads (16B-aligned, broadcast reads, no conflicts):
        // x64u[s] = x[64tc+s]; b64[s] = bnd row 64tc+s+1 (index 64tc+68+s).
        float x64u[64], b64[64];
#pragma unroll
        for (int j = 0; j < 16; ++j)
            *(float4*)&x64u[4 * j] = *(const float4*)&xl[64 * tc + 4 * j];
#pragma unroll
        for (int j = 0; j < 16; ++j)
            *(float4*)&b64[4 * j] = *(const float4*)&br[64 * tc + 68 + 4 * j];

        // boundary write: lane 63 (row r = 64tc+s-63) -> bnd[wv+1][64tc+4+s];
        // others -> dump.
        float* va = (lane == 63) ? &bnd[wv + 1][64 * tc + 4] : &dump[lane];

        STEP8(0) STEP8(8) STEP8(16) STEP8(24) STEP8(32) STEP8(40) STEP8(48) STEP8(56)

        // publish chunk tc (release orders the ds_writes above before the flag)
        __hip_atomic_store(&flagsA[wv + 1], tc + 1, __ATOMIC_RELEASE,
                           __HIP_MEMORY_SCOPE_WORKGROUP);
    }
#undef STEP
#undef STEP8

    // D[1023,1023]: wave 3 lane 63 col e=3 at t=1086 (chunk 16, s=62) -> c3
    // -> bnd[NW][1023+BOFF] = bnd[NW][1090]; read back from LDS, then
    // publish the completion ticket (store -> fence -> device atomicAdd).
    if (wv == NW - 1 && lane == 0) {
        dists[pair] = bnd[NW][1090];
        __threadfence();
        int old = __hip_atomic_fetch_add(cnt, 1, __ATOMIC_ACQ_REL,
                                         __HIP_MEMORY_SCOPE_AGENT);
        if (old == NSEG * NSEG - 1) lastFlag = 1;   // this block runs epilogue
    }
    __syncthreads();
    if (!lastFlag) return;

    // ---- fused epilogue (one block): softmax rows, then weighted sum ----
    if (tid < NSEG) {
        float l[NSEG], mx = -FLT_MAX;
#pragma unroll
        for (int j = 0; j < NSEG; ++j) {
            l[j] = 0.5f * dists[tid * NSEG + j];
            mx = fmaxf(mx, l[j]);
        }
        float s = 0.f;
#pragma unroll
        for (int j = 0; j < NSEG; ++j) { l[j] = expf(l[j] - mx); s += l[j]; }
        const float inv = 1.f / s;
#pragma unroll
        for (int j = 0; j < NSEG; ++j) wgt[tid][j] = l[j] * inv;
    }
    __syncthreads();
    for (int o = tid; o < NSEG * SEGLEN; o += 256) {
        const int i = o >> 10;
        const int p = o & 1023;
        float acc = 0.f;
#pragma unroll
        for (int j = 0; j < NSEG; ++j) acc += wgt[i][j] * vv[j * SEGLEN + p];
        out[o] = acc;
    }
}

extern "C" void kernel_launch(void* const* d_in, const int* in_sizes, int n_in,
                              void* d_out, int out_size, void* d_ws, size_t ws_size,
                              hipStream_t stream) {
    const float* q = (const float*)d_in[0];   // queries [1,32,8,32] f32
    const float* k = (const float*)d_in[1];   // keys
    const float* v = (const float*)d_in[2];   // values
    float* out = (float*)d_out;               // [8192] f32
    float* dists = (float*)d_ws;              // 64 floats scratch
    int* cnt = (int*)((char*)d_ws + 256);     // completion ticket counter

    hipMemsetAsync(cnt, 0, sizeof(int), stream);
    dtw_pl_kernel<<<dim3(NSEG * NSEG), dim3(256), 0, stream>>>(q, k, v, out,
                                                               dists, cnt);
}

// Round 26
// 55.458 us; speedup vs baseline: 1.4850x; 1.2141x over previous
//
#include <hip/hip_runtime.h>
#include <float.h>

#define NSEG 8
#define SEGLEN 1024   // B*Ls*H*D = 1*4*8*32
#define BIGV 1e30f    // "infinity" for invalid DP cells
#define PADV 1e18f    // x-pad sentinel: huge cost, no overflow over a chunk

#define NW 4          // waves per block (256 threads); wave owns 256 cols
#define CH 64         // steps per chunk (one flag handshake per chunk)
#define NCH 17        // local steps 0..1087 (lane 63 hits row 1023 at t=1086)
#define XLEN 1152     // xl[t] = x[t] for t<1024, else PADV
#define BOFF 67       // bnd[w][row + 67]; 67 chosen so preload base 64tc+68
                      // is 16B-aligned (uniform ds_read_b128)
#define BSTRIDE 1160  // max read index 64*16+68+63 = 1155

#define DPPF(OLD, SRC, CTRL, RM, BM, BC)                                      \
    __int_as_float(__builtin_amdgcn_update_dpp(                               \
        __float_as_int(OLD), __float_as_int(SRC), CTRL, RM, BM, BC))
// lane i <- lane i-1; lane 0 <- OLD[lane 0]   (validated R2-R25)
#define WSHIFT1(OLD, SRC) DPPF(OLD, SRC, 0x138, 0xF, 0xF, false)

// Lane-skewed systolic DTW, 4 waves (1 per SIMD) -- the measured optimum
// (R22: 50.6us kernel / 55.5us total). Wave w owns cols [256w,256w+256);
// lane L owns c_e = 256w+4L+e, e in 0..3.
// At local step t, lane L computes ROW r = t - L of its four columns:
//   c0 = |x[r]-y0| + min3(P0(up), lf(left), dgl(diag))
//   c_e = |x[r]-y_e| + min3(P_e, c_{e-1}, P_{e-1})
// lf/dgl arrive via one end-of-step wf_sr1 of c3; x travels the same way.
// FINAL MODEL (15 variants, R9-R25): latency-bound on the 1472-step critical
// path at ~4.3 cyc/inst single-wave dependent-issue cadence with ~16
// irreducible VALU inst/step. A/B-nulled: chain reassociation (R21), min3
// asm (R14), SGPR-hazard hoisting beyond R15, delayed DPPs (R19/R20),
// scan-form (R13/R16), RS=2 (R18), 2-pair packing (R24: better throughput,
// longer makespan), register write-buffering (R23: spills), epilogue fusion
// (R25: serial-tail > launch saving). Wins kept: anti-diagonal d-form (R3),
// multi-wave strip pipeline + flag handshake (R4/R6), skew-1 systolic (R10),
// 1 wave/SIMD (R12), group-hoisted injects (R15), uniform ds_read_b128
// register preloads for both injects (R22).
// Garbage rows (r<0, r>1023) carry PADV-scale costs acting as +inf.
// Lane 63 writes c3 (row r=t-63) to bnd[wv+1][64tc+4+s] per step (others
// hit a dump sink, branchless); monotone chunk-counter handshake with lag 2
// (consumer chunk tc reads bnd rows <= 64tc+64).
__global__ __launch_bounds__(256) void dtw_pl_kernel(const float* __restrict__ q,
                                                     const float* __restrict__ kk,
                                                     float* __restrict__ dists) {
    __shared__ float xl[XLEN];
    __shared__ float bnd[NW + 1][BSTRIDE];  // bnd[0] = BIGV region for wave 0
    __shared__ float dump[128];             // sink, indices up to 125 (R8 lesson)
    __shared__ int flagsA[NW + 1];          // [0]=sentinel; [w+1]=wave w chunks done
    const int tid = threadIdx.x;
    const int lane = tid & 63;
    const int wv = tid >> 6;
    const int pair = blockIdx.x;            // 0..63
    const float* __restrict__ x = q + (pair >> 3) * SEGLEN;
    const float* __restrict__ y = kk + (pair & 7) * SEGLEN;

    for (int t = tid; t < XLEN; t += 256) xl[t] = (t < SEGLEN) ? x[t] : PADV;
    // flat index 66 = bnd[0][BOFF-1] = virtual corner D[-1,-1] = 0; rest BIGV.
    for (int t = tid; t < (NW + 1) * BSTRIDE; t += 256)
        (&bnd[0][0])[t] = (t == BOFF - 1) ? 0.f : BIGV;
    if (tid < NW + 1) flagsA[tid] = (tid == 0) ? 0x7FFFFFFF : 0;

    const float4 y4 = *(const float4*)(y + wv * 256 + lane * 4);
    const float yv0 = y4.x, yv1 = y4.y, yv2 = y4.z, yv3 = y4.w;

    __syncthreads();   // the only block-wide barrier

    const float* __restrict__ br = &bnd[wv][0];   // left neighbor's boundary

    // wait for the first 2 producer chunks before reading init boundary
    {
        const int need0 = (NCH < 2) ? NCH : 2;
        while (__hip_atomic_load(&flagsA[wv], __ATOMIC_ACQUIRE,
                                 __HIP_MEMORY_SCOPE_WORKGROUP) < need0)
            __builtin_amdgcn_s_sleep(1);
    }
    float P0 = BIGV, P1 = BIGV, P2 = BIGV, P3 = BIGV, xreg = PADV;
    float lf = br[BOFF];       // D[0, 256w-1] (wave 0: BIGV); real only lane 0
    float dgl = br[BOFF - 1];  // D[-1,256w-1] (wave 0: corner 0)

// One systolic step; inject values come straight from the preloaded
// register arrays (static index s) as DPP old-operands.
#define STEP(s) {                                                             \
    xreg = WSHIFT1(x64u[(s)], xreg);                                          \
    const float c0n = fabsf(xreg - yv0) + fminf(fminf(P0, lf), dgl);          \
    const float c1n = fabsf(xreg - yv1) + fminf(fminf(P1, c0n), P0);          \
    const float c2n = fabsf(xreg - yv2) + fminf(fminf(P2, c1n), P1);          \
    const float c3n = fabsf(xreg - yv3) + fminf(fminf(P3, c2n), P2);          \
    const float n1 = WSHIFT1(b64[(s)], c3n);                                  \
    dgl = lf; lf = n1; P0 = c0n; P1 = c1n; P2 = c2n; P3 = c3n;                \
    va[(s)] = c3n;                                                            \
}
#define STEP8(s) STEP(s) STEP((s)+1) STEP((s)+2) STEP((s)+3)                  \
                 STEP((s)+4) STEP((s)+5) STEP((s)+6) STEP((s)+7)

#pragma unroll 1
    for (int tc = 0; tc < NCH; ++tc) {
        // consumer chunk tc reads bnd rows <= 64tc+64; producer writes row r
        // at its step r+63 -> needs chunk tc+1 done (flag >= tc+2), capped
        // at NCH (later indices are BIGV pad).
        const int need = (tc + 2 < NCH) ? (tc + 2) : NCH;
        while (__hip_atomic_load(&flagsA[wv], __ATOMIC_ACQUIRE,
                                 __HIP_MEMORY_SCOPE_WORKGROUP) < need)
            __builtin_amdgcn_s_sleep(1);

        // uniform preloads (16B-aligned, broadcast reads, no conflicts):
        // x64u[s] = x[64tc+s]; b64[s] = bnd row 64tc+s+1 (index 64tc+68+s).
        float x64u[64], b64[64];
#pragma unroll
        for (int j = 0; j < 16; ++j)
            *(float4*)&x64u[4 * j] = *(const float4*)&xl[64 * tc + 4 * j];
#pragma unroll
        for (int j = 0; j < 16; ++j)
            *(float4*)&b64[4 * j] = *(const float4*)&br[64 * tc + 68 + 4 * j];

        // boundary write: lane 63 (row r = 64tc+s-63) -> bnd[wv+1][64tc+4+s];
        // others -> dump.
        float* va = (lane == 63) ? &bnd[wv + 1][64 * tc + 4] : &dump[lane];

        STEP8(0) STEP8(8) STEP8(16) STEP8(24) STEP8(32) STEP8(40) STEP8(48) STEP8(56)

        // publish chunk tc (release orders the ds_writes above before the flag)
        __hip_atomic_store(&flagsA[wv + 1], tc + 1, __ATOMIC_RELEASE,
                           __HIP_MEMORY_SCOPE_WORKGROUP);
    }
#undef STEP
#undef STEP8

    // D[1023,1023]: wave 3 lane 63 col e=3 at t=1086 (chunk 16, s=62) -> c3
    // -> bnd[NW][1023+BOFF] = bnd[NW][1090]; read back from LDS.
    if (wv == NW - 1 && lane == 0) dists[pair] = bnd[NW][1090];
}

// out[i*1024+p] = sum_j softmax_j(0.5*dists[i,:])[j] * values[j*1024+p]
__global__ __launch_bounds__(256) void softmax_out_kernel(const float* __restrict__ v,
                                                          const float* __restrict__ dists,
                                                          float* __restrict__ out) {
    const int o = blockIdx.x * blockDim.x + threadIdx.x;
    if (o >= NSEG * SEGLEN) return;
    const int i = o >> 10;
    const int p = o & 1023;

    float l[NSEG];
    float mx = -FLT_MAX;
#pragma unroll
    for (int j = 0; j < NSEG; ++j) {
        l[j] = 0.5f * dists[i * NSEG + j];
        mx = fmaxf(mx, l[j]);
    }
    float s = 0.f;
#pragma unroll
    for (int j = 0; j < NSEG; ++j) {
        l[j] = expf(l[j] - mx);
        s += l[j];
    }
    const float inv = 1.f / s;
    float acc = 0.f;
#pragma unroll
    for (int j = 0; j < NSEG; ++j) acc += (l[j] * inv) * v[j * SEGLEN + p];
    out[o] = acc;
}

extern "C" void kernel_launch(void* const* d_in, const int* in_sizes, int n_in,
                              void* d_out, int out_size, void* d_ws, size_t ws_size,
                              hipStream_t stream) {
    const float* q = (const float*)d_in[0];   // queries [1,32,8,32] f32
    const float* k = (const float*)d_in[1];   // keys
    const float* v = (const float*)d_in[2];   // values
    float* out = (float*)d_out;               // [8192] f32
    float* dists = (float*)d_ws;              // 64 floats scratch

    dtw_pl_kernel<<<dim3(NSEG * NSEG), dim3(256), 0, stream>>>(q, k, dists);
    softmax_out_kernel<<<dim3((NSEG * SEGLEN + 255) / 256), dim3(256), 0, stream>>>(v, dists, out);
}